// Round 2
// baseline (602.666 us; speedup 1.0000x reference)
//
#include <hip/hip_runtime.h>
#include <math.h>

// GreedyRouter: softmax gating + top-8 + renormalize + histogram.
// Insight: renormalized top-k softmax == softmax over only the top-k logits
// (full-row denominator cancels), so we never compute the full softmax.
//
// R1: software-pipelined double-buffered LDS staging. Issue chunk c+1's
// global loads BEFORE consuming chunk c; commit (passthrough store + LDS
// write into other buffer) AFTER; ONE barrier per chunk. CHUNK=16 keeps
// LDS at 35840 B -> 4 blocks/CU (16 waves), same occupancy as before.

constexpr int NEXP   = 256;   // experts
constexpr int TOPK   = 8;
constexpr int TPB    = 256;   // threads per block == tokens per block
constexpr int CHUNK  = 16;    // columns staged per pipeline stage
constexpr int NCHUNK = NEXP / CHUNK;   // 16
constexpr int LDS_STRIDE = CHUNK + 1;  // 17: consume reads 2-way -> free
constexpr int F4T    = 4;     // float4 loads per thread per chunk

__global__ __launch_bounds__(TPB) void router_kernel(
    const float* __restrict__ logits,
    float* __restrict__ out_logits,
    float* __restrict__ out_w,
    float* __restrict__ out_id,
    float* __restrict__ counts)
{
    __shared__ float tile[2][TPB * LDS_STRIDE];   // 2 x 17408 B
    __shared__ int   hist[NEXP];                  // 1024 B

    const int tid  = threadIdx.x;
    const int tok0 = blockIdx.x * TPB;

    hist[tid] = 0;

    // per-thread sorted top-8 (descending); strict '>' + ascending index scan
    // reproduces jax.lax.top_k tie-breaking (lower index ranks first).
    float v[TOPK];
    int   id[TOPK];
#pragma unroll
    for (int k = 0; k < TOPK; ++k) { v[k] = -INFINITY; id[k] = 0; }

    // Static per-thread addressing for the 4 staged float4s of each chunk.
    // f = tid + 256*i -> row rr = f/4 (0..255), col-group cc = f%4.
    // Wave = 16 rows x 64 B row-slices; the other 64 B half of each 128 B
    // line is touched by the adjacent chunk one iteration later (L1/L2 hit).
    size_t gbase[F4T];
    int    lbase[F4T];
#pragma unroll
    for (int i = 0; i < F4T; ++i) {
        int f  = tid + TPB * i;
        int rr = f >> 2;
        int cc = f & 3;
        gbase[i] = (size_t)(tok0 + rr) * NEXP + cc * 4;
        lbase[i] = rr * LDS_STRIDE + cc * 4;
    }

    float4 x[F4T];

    // ---- prologue: load + commit chunk 0 into buffer 0 ----
#pragma unroll
    for (int i = 0; i < F4T; ++i)
        x[i] = *(const float4*)(logits + gbase[i]);
#pragma unroll
    for (int i = 0; i < F4T; ++i) {
        *(float4*)(out_logits + gbase[i]) = x[i];   // fused passthrough
        float* t = &tile[0][lbase[i]];              // scalar writes: stride 17
        t[0] = x[i].x; t[1] = x[i].y; t[2] = x[i].z; t[3] = x[i].w;
    }
    __syncthreads();

    // ---- main pipeline: one barrier per chunk ----
#pragma unroll 1
    for (int c = 0; c < NCHUNK; ++c) {
        const int  cur  = c & 1;
        const bool more = (c + 1 < NCHUNK);
        const int  cn   = (c + 1) * CHUNK;

        // 1) issue next chunk's global loads (latency hides under consume)
        if (more) {
#pragma unroll
            for (int i = 0; i < F4T; ++i)
                x[i] = *(const float4*)(logits + gbase[i] + cn);
        }

        // 2) consume current chunk: each thread scans its own token's 16 vals
        const float* row = &tile[cur][tid * LDS_STRIDE];
        const int c0 = c * CHUNK;
#pragma unroll
        for (int j = 0; j < CHUNK; ++j) {
            float xx = row[j];
            int   xi = c0 + j;
            // branch-free bubble insert into sorted-8
#pragma unroll
            for (int k = 0; k < TOPK; ++k) {
                bool  gt = xx > v[k];
                float tv = v[k];
                int   ti = id[k];
                v[k]  = gt ? xx : tv;
                id[k] = gt ? xi : ti;
                xx    = gt ? tv : xx;
                xi    = gt ? ti : xi;
            }
        }

        // 3) commit next chunk into the other buffer + fused passthrough
        if (more) {
#pragma unroll
            for (int i = 0; i < F4T; ++i) {
                *(float4*)(out_logits + gbase[i] + cn) = x[i];
                float* t = &tile[cur ^ 1][lbase[i]];
                t[0] = x[i].x; t[1] = x[i].y; t[2] = x[i].z; t[3] = x[i].w;
            }
        }
        __syncthreads();
    }

    // ---- epilogue: softmax over the selected 8 (== renormalized softmax) ----
    float e[TOPK];
    float s = 0.f;
#pragma unroll
    for (int k = 0; k < TOPK; ++k) { e[k] = __expf(v[k] - v[0]); s += e[k]; }
    const float inv = 1.0f / s;

    const size_t token = (size_t)(tok0 + tid);
    float4 w0 = make_float4(e[0] * inv, e[1] * inv, e[2] * inv, e[3] * inv);
    float4 w1 = make_float4(e[4] * inv, e[5] * inv, e[6] * inv, e[7] * inv);
    float4 i0 = make_float4((float)id[0], (float)id[1], (float)id[2], (float)id[3]);
    float4 i1 = make_float4((float)id[4], (float)id[5], (float)id[6], (float)id[7]);
    *(float4*)(out_w  + token * TOPK)     = w0;
    *(float4*)(out_w  + token * TOPK + 4) = w1;
    *(float4*)(out_id + token * TOPK)     = i0;
    *(float4*)(out_id + token * TOPK + 4) = i1;

#pragma unroll
    for (int k = 0; k < TOPK; ++k) atomicAdd(&hist[id[k]], 1);
    __syncthreads();
    // one global atomic per (block, expert)
    atomicAdd(&counts[tid], (float)hist[tid]);
}

extern "C" void kernel_launch(void* const* d_in, const int* in_sizes, int n_in,
                              void* d_out, int out_size, void* d_ws, size_t ws_size,
                              hipStream_t stream) {
    const float* logits = (const float*)d_in[0];
    const int n_tokens  = in_sizes[0] / NEXP;

    float* out        = (float*)d_out;
    float* out_logits = out;
    float* out_w      = out_logits + (size_t)n_tokens * NEXP;
    float* out_id     = out_w      + (size_t)n_tokens * TOPK;
    float* counts     = out_id     + (size_t)n_tokens * TOPK;

    // d_out is re-poisoned to 0xAA before every launch; histogram needs zeros.
    hipMemsetAsync(counts, 0, NEXP * sizeof(float), stream);

    const int blocks = n_tokens / TPB;  // 262144/256 = 1024
    router_kernel<<<blocks, TPB, 0, stream>>>(logits, out_logits, out_w,
                                              out_id, counts);
}

// Round 3
// 591.199 us; speedup vs baseline: 1.0194x; 1.0194x over previous
//
#include <hip/hip_runtime.h>
#include <math.h>

// GreedyRouter: softmax gating + top-8 + renormalize + histogram.
// Insight: renormalized top-k softmax == softmax over only the top-k logits
// (full-row denominator cancels), so we never compute the full softmax.
//
// R2: BARRIER-FREE main loop via per-WAVE staging. R1's counters showed
// both pipes idle (VALUBusy 23.6%, HBM 24%) -> stall-bound. The per-chunk
// __syncthreads drains vmcnt(0) (incl. passthrough stores) and phase-locks
// all resident waves. Fix: each wave owns 64 tokens and a private LDS
// slice; producer==consumer wave, so in-order lgkmcnt waits suffice and
// the K-loop needs NO barriers. Waves slip freely; store-acks never stall.

constexpr int NEXP   = 256;   // experts
constexpr int TOPK   = 8;
constexpr int TPB    = 256;   // 4 waves per block
constexpr int WAVES  = TPB / 64;
constexpr int CHUNK  = 16;    // columns staged per pipeline stage
constexpr int NCHUNK = NEXP / CHUNK;   // 16
constexpr int STRIDE = CHUNK + 1;      // 17: read bank=(17*lane+j)%32 -> 2-way, free
constexpr int F4T    = 4;     // float4 loads per lane per chunk (64 rows * 64B)

__global__ __launch_bounds__(TPB) void router_kernel(
    const float* __restrict__ logits,
    float* __restrict__ out_logits,
    float* __restrict__ out_w,
    float* __restrict__ out_id,
    float* __restrict__ counts)
{
    __shared__ float tile[WAVES][2][64 * STRIDE];   // 4*2*4352B = 34816 B
    __shared__ int   hist[NEXP];                    // 1024 B -> 35840 total

    const int tid  = threadIdx.x;
    const int wave = tid >> 6;
    const int lane = tid & 63;
    const int tokw0 = blockIdx.x * TPB + wave * 64;   // this wave's 64 tokens

    hist[tid] = 0;
    __syncthreads();   // hist init visible before any wave's atomics (only
                       // barrier besides the final reduction one)

    // per-thread sorted top-8 (descending); strict '>' + ascending index scan
    // reproduces jax.lax.top_k tie-breaking (lower index ranks first).
    float v[TOPK];
    int   id[TOPK];
#pragma unroll
    for (int k = 0; k < TOPK; ++k) { v[k] = -INFINITY; id[k] = 0; }

    // Static addressing: f = lane + 64*i -> row rr = f/4 (0..63), col-group
    // cc = f%4. Wave-load = 16 rows x 64B segments per instr (coalesced).
    size_t gbase[F4T];
    int    lbase[F4T];
#pragma unroll
    for (int i = 0; i < F4T; ++i) {
        int f  = lane + 64 * i;
        int rr = f >> 2;
        int cc = f & 3;
        gbase[i] = (size_t)(tokw0 + rr) * NEXP + cc * 4;
        lbase[i] = rr * STRIDE + cc * 4;
    }

    float4 x[F4T];

    // ---- prologue: load + commit chunk 0 into buffer 0 (no barrier) ----
#pragma unroll
    for (int i = 0; i < F4T; ++i)
        x[i] = *(const float4*)(logits + gbase[i]);
#pragma unroll
    for (int i = 0; i < F4T; ++i) {
        *(float4*)(out_logits + gbase[i]) = x[i];    // fused passthrough
        float* t = &tile[wave][0][lbase[i]];         // scalar: stride 17 not
        t[0] = x[i].x; t[1] = x[i].y; t[2] = x[i].z; t[3] = x[i].w; // 16B-aligned
    }

    // ---- main pipeline: ZERO barriers ----
#pragma unroll 1
    for (int c = 0; c < NCHUNK; ++c) {
        const bool more = (c + 1 < NCHUNK);
        const int  cn   = (c + 1) * CHUNK;

        // 1) issue next chunk's global loads (latency hides under consume)
        if (more) {
#pragma unroll
            for (int i = 0; i < F4T; ++i)
                x[i] = *(const float4*)(logits + gbase[i] + cn);
        }

        // 2) consume current chunk: each lane scans its own token's 16 vals
        //    (written by THIS wave last iteration; in-order lgkmcnt suffices)
        const float* row = &tile[wave][c & 1][lane * STRIDE];
        const int c0 = c * CHUNK;
#pragma unroll
        for (int j = 0; j < CHUNK; ++j) {
            float xx = row[j];
            int   xi = c0 + j;
            // branch-free bubble insert into sorted-8
#pragma unroll
            for (int k = 0; k < TOPK; ++k) {
                bool  gt = xx > v[k];
                float tv = v[k];
                int   ti = id[k];
                v[k]  = gt ? xx : tv;
                id[k] = gt ? xi : ti;
                xx    = gt ? tv : xx;
                xi    = gt ? ti : xi;
            }
        }

        // 3) commit next chunk into the other buffer + fused passthrough
        if (more) {
            float* tnext = tile[wave][(c + 1) & 1];
#pragma unroll
            for (int i = 0; i < F4T; ++i) {
                *(float4*)(out_logits + gbase[i] + cn) = x[i];
                float* t = tnext + lbase[i];
                t[0] = x[i].x; t[1] = x[i].y; t[2] = x[i].z; t[3] = x[i].w;
            }
        }
    }

    // ---- epilogue: softmax over the selected 8 (== renormalized softmax) ----
    float e[TOPK];
    float s = 0.f;
#pragma unroll
    for (int k = 0; k < TOPK; ++k) { e[k] = __expf(v[k] - v[0]); s += e[k]; }
    const float inv = 1.0f / s;

    const size_t token = (size_t)(tokw0 + lane);
    float4 w0 = make_float4(e[0] * inv, e[1] * inv, e[2] * inv, e[3] * inv);
    float4 w1 = make_float4(e[4] * inv, e[5] * inv, e[6] * inv, e[7] * inv);
    float4 i0 = make_float4((float)id[0], (float)id[1], (float)id[2], (float)id[3]);
    float4 i1 = make_float4((float)id[4], (float)id[5], (float)id[6], (float)id[7]);
    *(float4*)(out_w  + token * TOPK)     = w0;
    *(float4*)(out_w  + token * TOPK + 4) = w1;
    *(float4*)(out_id + token * TOPK)     = i0;
    *(float4*)(out_id + token * TOPK + 4) = i1;

#pragma unroll
    for (int k = 0; k < TOPK; ++k) atomicAdd(&hist[id[k]], 1);
    __syncthreads();
    // one global atomic per (block, expert)
    atomicAdd(&counts[tid], (float)hist[tid]);
}

extern "C" void kernel_launch(void* const* d_in, const int* in_sizes, int n_in,
                              void* d_out, int out_size, void* d_ws, size_t ws_size,
                              hipStream_t stream) {
    const float* logits = (const float*)d_in[0];
    const int n_tokens  = in_sizes[0] / NEXP;

    float* out        = (float*)d_out;
    float* out_logits = out;
    float* out_w      = out_logits + (size_t)n_tokens * NEXP;
    float* out_id     = out_w      + (size_t)n_tokens * TOPK;
    float* counts     = out_id     + (size_t)n_tokens * TOPK;

    // d_out is re-poisoned to 0xAA before every launch; histogram needs zeros.
    hipMemsetAsync(counts, 0, NEXP * sizeof(float), stream);

    const int blocks = n_tokens / TPB;  // 262144/256 = 1024
    router_kernel<<<blocks, TPB, 0, stream>>>(logits, out_logits, out_w,
                                              out_id, counts);
}

// Round 4
// 515.182 us; speedup vs baseline: 1.1698x; 1.1476x over previous
//
#include <hip/hip_runtime.h>
#include <math.h>

// GreedyRouter: softmax gating + top-8 + renormalize + histogram.
// Insight: renormalized top-k softmax == softmax over only the top-k logits
// (full-row denominator cancels), so we never compute the full softmax.
//
// R3: fix the vmcnt store-ack serialization. vmcnt retires IN ISSUE ORDER;
// R2 used freshly-issued loads (newest VMEM) right away, so the compiler's
// wait also drained the previous iteration's passthrough stores -> every
// wave stalled on store-ack each chunk (VALUBusy 25%, HBM 25%, both idle).
// Now: rotated register double-buffer. Issue L(c+1) FIRST, then use L(c)
// (issued one whole iteration ago, OLDEST outstanding) -> compiler emits a
// counted vmcnt that keeps stores + next loads in flight. Zero loop
// barriers (per-wave staging, producer==consumer). Single LDS buffer.

constexpr int NEXP   = 256;   // experts
constexpr int TOPK   = 8;
constexpr int TPB    = 256;   // 4 waves per block
constexpr int WAVES  = TPB / 64;
constexpr int CHUNK  = 16;    // columns staged per pipeline stage
constexpr int NCHUNK = NEXP / CHUNK;   // 16
constexpr int STRIDE = CHUNK + 1;      // 17: read bank=(17*lane+j)%32 -> 2-way, free
constexpr int F4T    = 4;     // float4 loads per lane per chunk

__global__ __launch_bounds__(TPB) void router_kernel(
    const float* __restrict__ logits,
    float* __restrict__ out_logits,
    float* __restrict__ out_w,
    float* __restrict__ out_id,
    float* __restrict__ counts)
{
    __shared__ float tile[WAVES][64 * STRIDE];   // 4 x 4352 B (single buffer)
    __shared__ int   hist[NEXP];                 // 1024 B -> 18432 B total

    const int tid  = threadIdx.x;
    const int wave = tid >> 6;
    const int lane = tid & 63;
    const int tokw0 = blockIdx.x * TPB + wave * 64;   // this wave's 64 tokens

    hist[tid] = 0;
    __syncthreads();   // hist zeroed before any wave's atomics

    // per-thread sorted top-8 (descending); strict '>' + ascending index scan
    // reproduces jax.lax.top_k tie-breaking (lower index ranks first).
    float v[TOPK];
    int   id[TOPK];
#pragma unroll
    for (int k = 0; k < TOPK; ++k) { v[k] = -INFINITY; id[k] = 0; }

    // Static addressing: f = lane + 64*i -> row rr = f/4 (0..63), col-group
    // cc = f%4. Wave-load = 16 rows x 64B segments per instr (coalesced).
    size_t gbase[F4T];
    int    lbase[F4T];
#pragma unroll
    for (int i = 0; i < F4T; ++i) {
        int f  = lane + 64 * i;
        int rr = f >> 2;
        int cc = f & 3;
        gbase[i] = (size_t)(tokw0 + rr) * NEXP + cc * 4;
        lbase[i] = rr * STRIDE + cc * 4;
    }

    // Named rotated buffers (runtime-indexed arrays would go to scratch).
    float4 xA[F4T], xB[F4T];

    // One pipeline step: chunk C is in XC (loads issued one step earlier).
    // Order matters: (1) issue L(C+1) into XN, (2) use XC (LDS commit +
    // passthrough store -- compiler waits on the OLDEST vmcnt entries only),
    // (3) consume chunk C from LDS (in-wave lgkmcnt ordering, no barrier).
#define STEP(C, XC, XN)                                                     \
    {                                                                       \
        const int c_ = (C);                                                 \
        if (c_ + 1 < NCHUNK) {                                              \
            const int off = (c_ + 1) * CHUNK;                               \
            _Pragma("unroll")                                               \
            for (int i = 0; i < F4T; ++i)                                   \
                XN[i] = *(const float4*)(logits + gbase[i] + off);          \
        }                                                                   \
        {                                                                   \
            const int off = c_ * CHUNK;                                     \
            _Pragma("unroll")                                               \
            for (int i = 0; i < F4T; ++i) {                                 \
                *(float4*)(out_logits + gbase[i] + off) = XC[i];            \
                float* t = &tile[wave][lbase[i]];                           \
                t[0] = XC[i].x; t[1] = XC[i].y;                             \
                t[2] = XC[i].z; t[3] = XC[i].w;                             \
            }                                                               \
        }                                                                   \
        const float* row = &tile[wave][lane * STRIDE];                      \
        const int c0 = c_ * CHUNK;                                          \
        _Pragma("unroll")                                                   \
        for (int j = 0; j < CHUNK; ++j) {                                   \
            float xx = row[j];                                              \
            int   xi = c0 + j;                                              \
            _Pragma("unroll")                                               \
            for (int k = 0; k < TOPK; ++k) {                                \
                bool  gt = xx > v[k];                                       \
                float tv = v[k];                                            \
                int   ti = id[k];                                           \
                v[k]  = gt ? xx : tv;                                       \
                id[k] = gt ? xi : ti;                                       \
                xx    = gt ? tv : xx;                                       \
                xi    = gt ? ti : xi;                                       \
            }                                                               \
        }                                                                   \
    }

    // ---- prologue: issue chunk 0 loads into xA ----
#pragma unroll
    for (int i = 0; i < F4T; ++i)
        xA[i] = *(const float4*)(logits + gbase[i]);

    // ---- main pipeline: zero barriers, stores never awaited ----
#pragma unroll 1
    for (int c = 0; c < NCHUNK; c += 2) {
        STEP(c,     xA, xB);
        STEP(c + 1, xB, xA);
    }
#undef STEP

    // ---- epilogue: softmax over the selected 8 (== renormalized softmax) ----
    float e[TOPK];
    float s = 0.f;
#pragma unroll
    for (int k = 0; k < TOPK; ++k) { e[k] = __expf(v[k] - v[0]); s += e[k]; }
    const float inv = 1.0f / s;

    const size_t token = (size_t)(tokw0 + lane);
    float4 w0 = make_float4(e[0] * inv, e[1] * inv, e[2] * inv, e[3] * inv);
    float4 w1 = make_float4(e[4] * inv, e[5] * inv, e[6] * inv, e[7] * inv);
    float4 i0 = make_float4((float)id[0], (float)id[1], (float)id[2], (float)id[3]);
    float4 i1 = make_float4((float)id[4], (float)id[5], (float)id[6], (float)id[7]);
    *(float4*)(out_w  + token * TOPK)     = w0;
    *(float4*)(out_w  + token * TOPK + 4) = w1;
    *(float4*)(out_id + token * TOPK)     = i0;
    *(float4*)(out_id + token * TOPK + 4) = i1;

#pragma unroll
    for (int k = 0; k < TOPK; ++k) atomicAdd(&hist[id[k]], 1);
    __syncthreads();
    // one global atomic per (block, expert)
    atomicAdd(&counts[tid], (float)hist[tid]);
}

extern "C" void kernel_launch(void* const* d_in, const int* in_sizes, int n_in,
                              void* d_out, int out_size, void* d_ws, size_t ws_size,
                              hipStream_t stream) {
    const float* logits = (const float*)d_in[0];
    const int n_tokens  = in_sizes[0] / NEXP;

    float* out        = (float*)d_out;
    float* out_logits = out;
    float* out_w      = out_logits + (size_t)n_tokens * NEXP;
    float* out_id     = out_w      + (size_t)n_tokens * TOPK;
    float* counts     = out_id     + (size_t)n_tokens * TOPK;

    // d_out is re-poisoned to 0xAA before every launch; histogram needs zeros.
    hipMemsetAsync(counts, 0, NEXP * sizeof(float), stream);

    const int blocks = n_tokens / TPB;  // 262144/256 = 1024
    router_kernel<<<blocks, TPB, 0, stream>>>(logits, out_logits, out_w,
                                              out_id, counts);
}